// Round 16
// baseline (172.036 us; speedup 1.0000x reference)
//
#include <hip/hip_runtime.h>

typedef __attribute__((__ext_vector_type__(8))) __bf16 bf16x8;
typedef __attribute__((__ext_vector_type__(4))) float f32x4;
typedef __attribute__((__ext_vector_type__(2))) float f32x2;
typedef __attribute__((__ext_vector_type__(4))) unsigned int u32x4;

__device__ __forceinline__ float bf2f(unsigned short u) {
    return __uint_as_float(((unsigned int)u) << 16);
}
__device__ __forceinline__ unsigned short f2bf(float f) {
    unsigned int u = __float_as_uint(f);
    u += 0x7FFFu + ((u >> 16) & 1u);   // RNE
    return (unsigned short)(u >> 16);
}

// ---------------------------------------------------------------------------
// Per-wave dtype probes (validated rounds 9-15).
// ---------------------------------------------------------------------------
__device__ __forceinline__ bool low_short_is_bf16like(unsigned int w) {
    unsigned int lo = w & 0xFFFFu;
    if (lo == 0u || lo == 0x8000u) return true;
    unsigned int e = (lo >> 7) & 0xFFu;
    return (e >= 0x6Cu && e <= 0x8Cu);
}
__device__ __forceinline__ int probe_f32(const unsigned int* __restrict__ p) {
    int t = threadIdx.x & 63;
    int cnt = __popcll(__ballot(low_short_is_bf16like(p[t])));
    return (cnt < 32) ? 1 : 0;
}
__device__ __forceinline__ int probe_e64(const unsigned int* __restrict__ ei) {
    int t = threadIdx.x & 63;
    unsigned int o1 = ei[2 * t + 1];
    unsigned int o2 = ei[2 * t + 129];
    return __all((o1 == 0u) && (o2 == 0u)) ? 1 : 0;
}

// ---------------------------------------------------------------------------
// Per-wave gather of one node's fp8-row mean into LDS (bf16). Shared by both
// fused GEMM kernels; identical math to the validated k_agg (rounds 10-15).
// ---------------------------------------------------------------------------
template <typename IT>
__device__ __forceinline__ void gather_mean_to_lds(
    const unsigned int* __restrict__ x8,
    const int* __restrict__ rowptr, const int* __restrict__ aux,
    const int* __restrict__ deg, const IT* __restrict__ adj,
    int rg, int h, int sl, unsigned short* __restrict__ ldsrow)
{
    int start = rowptr[rg] + aux[rg >> 10];
    int dc = deg[rg];
    float acc[4][4];
    #pragma unroll
    for (int u = 0; u < 4; u++)
        #pragma unroll
        for (int c = 0; c < 4; c++) acc[u][c] = 0.f;
    int i = 0;
    for (; i + 15 < dc; i += 16) {
        int e[8]; unsigned int p[8];
        #pragma unroll
        for (int u = 0; u < 8; u++) e[u] = (int)adj[start + i + 2 * u + h];
        #pragma unroll
        for (int u = 0; u < 8; u++) p[u] = x8[(size_t)e[u] * 32 + sl];
        #pragma unroll
        for (int u = 0; u < 8; u++) {
            f32x2 lo = __builtin_amdgcn_cvt_pk_f32_fp8((int)p[u], false);
            f32x2 hi = __builtin_amdgcn_cvt_pk_f32_fp8((int)p[u], true);
            acc[u & 3][0] += lo.x; acc[u & 3][1] += lo.y;
            acc[u & 3][2] += hi.x; acc[u & 3][3] += hi.y;
        }
    }
    if (i + 7 < dc) {
        int e[4]; unsigned int p[4];
        #pragma unroll
        for (int u = 0; u < 4; u++) e[u] = (int)adj[start + i + 2 * u + h];
        #pragma unroll
        for (int u = 0; u < 4; u++) p[u] = x8[(size_t)e[u] * 32 + sl];
        #pragma unroll
        for (int u = 0; u < 4; u++) {
            f32x2 lo = __builtin_amdgcn_cvt_pk_f32_fp8((int)p[u], false);
            f32x2 hi = __builtin_amdgcn_cvt_pk_f32_fp8((int)p[u], true);
            acc[u][0] += lo.x; acc[u][1] += lo.y;
            acc[u][2] += hi.x; acc[u][3] += hi.y;
        }
        i += 8;
    }
    for (; i + h < dc; i += 2) {
        int e0 = (int)adj[start + i + h];
        unsigned int p0 = x8[(size_t)e0 * 32 + sl];
        f32x2 lo = __builtin_amdgcn_cvt_pk_f32_fp8((int)p0, false);
        f32x2 hi = __builtin_amdgcn_cvt_pk_f32_fp8((int)p0, true);
        acc[0][0] += lo.x; acc[0][1] += lo.y; acc[0][2] += hi.x; acc[0][3] += hi.y;
    }
    float t0 = (acc[0][0] + acc[1][0]) + (acc[2][0] + acc[3][0]);
    float t1 = (acc[0][1] + acc[1][1]) + (acc[2][1] + acc[3][1]);
    float t2 = (acc[0][2] + acc[1][2]) + (acc[2][2] + acc[3][2]);
    float t3 = (acc[0][3] + acc[1][3]) + (acc[2][3] + acc[3][3]);
    t0 += __shfl_xor(t0, 32);
    t1 += __shfl_xor(t1, 32);
    t2 += __shfl_xor(t2, 32);
    t3 += __shfl_xor(t3, 32);
    if (h == 0) {
        float inv = 1.f / fmaxf((float)dc, 1.f);
        uint2 o;
        o.x = (unsigned int)f2bf(t0 * inv) | ((unsigned int)f2bf(t1 * inv) << 16);
        o.y = (unsigned int)f2bf(t2 * inv) | ((unsigned int)f2bf(t3 * inv) << 16);
        *(uint2*)&ldsrow[sl * 4] = o;
    }
}

// ---------------------------------------------------------------------------
// k_front: rank || tobf interleaved by block parity, fold at the tail.
// (validated rounds 13-15)
// ---------------------------------------------------------------------------
__device__ __forceinline__ void front_rank(
    int blk, int t, const int* __restrict__ ei, int* __restrict__ deg,
    int* __restrict__ rank, unsigned int* __restrict__ ds32,
    int E, int nnodes, int pack)
{
    int e64 = probe_e64((const unsigned int*)ei);
    int e = blk * 256 + t;
    if (e >= E) return;
    int s, d;
    if (e64) { s = ei[2 * e]; d = ei[2 * (E + e)]; }
    else     { s = ei[e];     d = ei[E + e]; }
    if ((unsigned)s >= (unsigned)nnodes) s = 0;
    int r = 0;
    if ((unsigned)d < (unsigned)nnodes) r = atomicAdd(&deg[d], 1);
    rank[e] = r;
    if (pack) ds32[e] = (((unsigned int)d & 0xFFFFu) << 16) | ((unsigned int)s & 0xFFFFu);
}

__device__ __forceinline__ void front_tobf(
    int blk, int t, const void* __restrict__ xv,
    unsigned short* __restrict__ xbf, unsigned int* __restrict__ x8, long nelem)
{
    int xf32 = probe_f32((const unsigned int*)xv);
    long i = ((long)blk * 256 + t) * 8;
    if (i >= nelem) return;
    float f[8];
    if (xf32) {
        const float4* p = (const float4*)((const float*)xv + i);
        float4 v0 = p[0], v1 = p[1];
        f[0] = v0.x; f[1] = v0.y; f[2] = v0.z; f[3] = v0.w;
        f[4] = v1.x; f[5] = v1.y; f[6] = v1.z; f[7] = v1.w;
        u32x4 o;
        o.x = (unsigned int)f2bf(f[0]) | ((unsigned int)f2bf(f[1]) << 16);
        o.y = (unsigned int)f2bf(f[2]) | ((unsigned int)f2bf(f[3]) << 16);
        o.z = (unsigned int)f2bf(f[4]) | ((unsigned int)f2bf(f[5]) << 16);
        o.w = (unsigned int)f2bf(f[6]) | ((unsigned int)f2bf(f[7]) << 16);
        *(u32x4*)&xbf[i] = o;
    } else {
        u32x4 v = *(const u32x4*)((const unsigned short*)xv + i);
        *(u32x4*)&xbf[i] = v;
        f[0] = bf2f((unsigned short)v.x); f[1] = bf2f((unsigned short)(v.x >> 16));
        f[2] = bf2f((unsigned short)v.y); f[3] = bf2f((unsigned short)(v.y >> 16));
        f[4] = bf2f((unsigned short)v.z); f[5] = bf2f((unsigned short)(v.z >> 16));
        f[6] = bf2f((unsigned short)v.w); f[7] = bf2f((unsigned short)(v.w >> 16));
    }
    unsigned int q0 = 0, q1 = 0;
    q0 = (unsigned int)__builtin_amdgcn_cvt_pk_fp8_f32(f[0], f[1], (int)q0, false);
    q0 = (unsigned int)__builtin_amdgcn_cvt_pk_fp8_f32(f[2], f[3], (int)q0, true);
    q1 = (unsigned int)__builtin_amdgcn_cvt_pk_fp8_f32(f[4], f[5], (int)q1, false);
    q1 = (unsigned int)__builtin_amdgcn_cvt_pk_fp8_f32(f[6], f[7], (int)q1, true);
    uint2 q; q.x = q0; q.y = q1;
    *(uint2*)&x8[i >> 2] = q;
}

__global__ __launch_bounds__(256) void k_front(
    const int* __restrict__ ei, int* __restrict__ deg, int* __restrict__ rank,
    unsigned int* __restrict__ ds32, int E, int nnodes, int pack, int egrid,
    const void* __restrict__ xv, unsigned short* __restrict__ xbf,
    unsigned int* __restrict__ x8, long nelem, int tgrid,
    const void* __restrict__ Wl, const void* __restrict__ Wr,
    const void* __restrict__ Wsk, const void* __restrict__ gamma,
    const void* __restrict__ rvar, const void* __restrict__ bl,
    const void* __restrict__ bsk, const void* __restrict__ rmean,
    const void* __restrict__ beta, const void* __restrict__ Wlo,
    const void* __restrict__ blo, const void* __restrict__ Wro,
    unsigned short* __restrict__ W1p, unsigned short* __restrict__ W2p,
    float* __restrict__ bias1, float* __restrict__ bias2)
{
    int blk = blockIdx.x, t = threadIdx.x;
    int mn = (egrid < tgrid) ? egrid : tgrid;
    int m2 = 2 * mn;
    if (blk < m2) {
        if (blk & 1) front_tobf(blk >> 1, t, xv, xbf, x8, nelem);
        else         front_rank(blk >> 1, t, ei, deg, rank, ds32, E, nnodes, pack);
        return;
    }
    if (blk < egrid + tgrid) {
        int r = blk - m2;
        if (egrid > tgrid) front_rank(mn + r, t, ei, deg, rank, ds32, E, nnodes, pack);
        else               front_tobf(mn + r, t, xv, xbf, x8, nelem);
        return;
    }
    // ---- fold ----
    int wf32 = probe_f32((const unsigned int*)Wl);
    int b = blk - egrid - tgrid;
    if (b < 128) {
        int idx = b * 256 + t;
        int kb = idx >> 10, c = (idx >> 3) & 127, k7 = idx & 7;
        int k = kb * 8 + k7;
        float g, rv, w;
        if (wf32) {
            g  = ((const float*)gamma)[c];
            rv = ((const float*)rvar)[c];
            if (k < 128) w = ((const float*)Wl)[k * 128 + c];
            else { int kk = k - 128;
                   w = ((const float*)Wr)[kk * 128 + c] + ((const float*)Wsk)[kk * 128 + c]; }
        } else {
            g  = bf2f(((const unsigned short*)gamma)[c]);
            rv = bf2f(((const unsigned short*)rvar)[c]);
            if (k < 128) w = bf2f(((const unsigned short*)Wl)[k * 128 + c]);
            else { int kk = k - 128;
                   w = bf2f(((const unsigned short*)Wr)[kk * 128 + c]) +
                       bf2f(((const unsigned short*)Wsk)[kk * 128 + c]); }
        }
        float s = g * rsqrtf(rv + 1e-5f);
        W1p[idx] = f2bf(w * s);
    } else if (b < 448) {
        int idx = (b - 128) * 256 + t;
        int kb = idx / 2560;
        int rem = idx - kb * 2560;
        int c = rem >> 3, k7 = idx & 7;
        int k = kb * 8 + k7;
        float w = 0.f;
        if (c < 300) {
            if (wf32)
                w = (k < 128) ? ((const float*)Wlo)[k * 300 + c]
                              : ((const float*)Wro)[(k - 128) * 300 + c];
            else
                w = (k < 128) ? bf2f(((const unsigned short*)Wlo)[k * 300 + c])
                              : bf2f(((const unsigned short*)Wro)[(k - 128) * 300 + c]);
        }
        W2p[idx] = f2bf(w);
    } else {
        if (t < 128) {
            float g, rv, b1, b2, rm, be;
            if (wf32) {
                g = ((const float*)gamma)[t]; rv = ((const float*)rvar)[t];
                b1 = ((const float*)bl)[t];   b2 = ((const float*)bsk)[t];
                rm = ((const float*)rmean)[t]; be = ((const float*)beta)[t];
            } else {
                g = bf2f(((const unsigned short*)gamma)[t]); rv = bf2f(((const unsigned short*)rvar)[t]);
                b1 = bf2f(((const unsigned short*)bl)[t]);   b2 = bf2f(((const unsigned short*)bsk)[t]);
                rm = bf2f(((const unsigned short*)rmean)[t]); be = bf2f(((const unsigned short*)beta)[t]);
            }
            float s = g * rsqrtf(rv + 1e-5f);
            bias1[t] = (b1 + b2 - rm) * s + be;
        }
        for (int c = t; c < 320; c += 256) {
            float v = 0.f;
            if (c < 300)
                v = wf32 ? ((const float*)blo)[c] : bf2f(((const unsigned short*)blo)[c]);
            bias2[c] = v;
        }
    }
}

// ---------------------------------------------------------------------------
// Fused two-level scan (validated rounds 14-15).
// ---------------------------------------------------------------------------
__global__ __launch_bounds__(256) void k_scan(
    const int* __restrict__ deg, int* __restrict__ rowptr,
    int* __restrict__ aux, int* __restrict__ scnt, int n, int nblk)
{
    __shared__ int wsum[4];
    __shared__ int lastflag;
    int t = threadIdx.x, blk = blockIdx.x;
    int base = blk * 1024 + t * 4;
    int v[4];
    int s = 0;
    #pragma unroll
    for (int i = 0; i < 4; i++) { int idx = base + i; v[i] = (idx < n) ? deg[idx] : 0; s += v[i]; }
    int lane = t & 63, wv = t >> 6;
    int inc = s;
    #pragma unroll
    for (int off = 1; off < 64; off <<= 1) {
        int u = __shfl_up(inc, off);
        if (lane >= off) inc += u;
    }
    if (lane == 63) wsum[wv] = inc;
    __syncthreads();
    int woff = 0;
    if (wv >= 1) woff += wsum[0];
    if (wv >= 2) woff += wsum[1];
    if (wv >= 3) woff += wsum[2];
    int exc = woff + inc - s;
    #pragma unroll
    for (int i = 0; i < 4; i++) { int idx = base + i; if (idx < n) rowptr[idx] = exc; exc += v[i]; }
    if (t == 255) {
        aux[blk] = woff + inc;
        __threadfence();
        int prev = atomicAdd(scnt, 1);
        lastflag = (prev == nblk - 1) ? 1 : 0;
    }
    __syncthreads();
    if (lastflag && t < 64) {
        __threadfence();
        int carry = 0;
        for (int b2 = 0; b2 < nblk; b2 += 64) {
            int idx = b2 + t;
            int av = (idx < nblk) ? aux[idx] : 0;
            int inc2 = av;
            #pragma unroll
            for (int off = 1; off < 64; off <<= 1) {
                int u = __shfl_up(inc2, off);
                if (t >= off) inc2 += u;
            }
            if (idx < nblk) aux[idx] = carry + inc2 - av;   // exclusive
            carry += __shfl(inc2, 63);
        }
    }
}

__global__ __launch_bounds__(256) void k_place16(
    const unsigned int* __restrict__ ds32,
    const int* __restrict__ rowptr, const int* __restrict__ aux,
    const int* __restrict__ rank,
    unsigned short* __restrict__ adj, int E, int nnodes)
{
    int e = blockIdx.x * 256 + threadIdx.x;
    if (e >= E) return;
    unsigned int ds = ds32[e];
    int d = (int)(ds >> 16);
    unsigned short s = (unsigned short)(ds & 0xFFFFu);
    if (d >= nnodes) return;
    adj[rowptr[d] + aux[d >> 10] + rank[e]] = s;
}

__global__ __launch_bounds__(256) void k_place32(
    const int* __restrict__ ei,
    const int* __restrict__ rowptr, const int* __restrict__ aux,
    const int* __restrict__ rank,
    int* __restrict__ adj, int E, int nnodes)
{
    int e64 = probe_e64((const unsigned int*)ei);
    int e = blockIdx.x * 256 + threadIdx.x;
    if (e >= E) return;
    int s, d;
    if (e64) { s = ei[2 * e]; d = ei[2 * (E + e)]; }
    else     { s = ei[e];     d = ei[E + e]; }
    if ((unsigned)d >= (unsigned)nnodes) return;
    if ((unsigned)s >= (unsigned)nnodes) s = 0;
    adj[rowptr[d] + aux[d >> 10] + rank[e]] = s;
}

// ---------------------------------------------------------------------------
// Fused agg+GEMM1 (32 rows/block): wave wv gathers nodes row0+wv*8..+7 into
// the A-tile LDS, then h = [mean | xbf] @ W1p + bias1. NT h-store, fused
// xemb8 repack, 2-deep B prefetch.
// ---------------------------------------------------------------------------
template <typename IT>
__global__ __launch_bounds__(256) void k_ag1(
    const unsigned int* __restrict__ x8,
    const int* __restrict__ rowptr, const int* __restrict__ aux,
    const int* __restrict__ deg, const IT* __restrict__ adj,
    const unsigned short* __restrict__ xbf, const unsigned int* __restrict__ xprobe,
    const unsigned short* __restrict__ Wp,
    const float* __restrict__ bias, void* __restrict__ outh,
    unsigned int* __restrict__ xemb8, int nrows)
{
    constexpr int NTW = 2;
    __shared__ __align__(16) unsigned short Alds[32 * 264];
    int tid = threadIdx.x;
    int row0 = blockIdx.x * 32;
    int xf32 = probe_f32(xprobe);
    {   // stage x self-term (cols 128..255)
        int r = tid >> 3, c0 = (tid & 7) * 16;
        int rg = row0 + r; if (rg >= nrows) rg = nrows - 1;
        const u32x4* xp = (const u32x4*)(xbf + (size_t)rg * 128 + c0);
        *(u32x4*)&Alds[r * 264 + 128 + c0]     = xp[0];
        *(u32x4*)&Alds[r * 264 + 128 + c0 + 8] = xp[1];
    }
    int lane = tid & 63, wv = tid >> 6, lh = lane & 15, lq = lane >> 4;
    {   // gather phase: wave wv aggregates its 8 rows into cols 0..127
        int h = lane >> 5, sl = lane & 31;
        for (int k = 0; k < 8; k++) {
            int rl = wv * 8 + k;
            int rg = row0 + rl; if (rg >= nrows) rg = nrows - 1;
            gather_mean_to_lds<IT>(x8, rowptr, aux, deg, adj, rg, h, sl,
                                   &Alds[rl * 264]);
        }
    }
    __syncthreads();
    f32x4 acc[2][NTW];
    #pragma unroll
    for (int a = 0; a < 2; a++)
        #pragma unroll
        for (int b = 0; b < NTW; b++) acc[a][b] = f32x4{0.f, 0.f, 0.f, 0.f};
    bf16x8 bcur[NTW], bnxt[NTW];
    #pragma unroll
    for (int i = 0; i < NTW; i++)
        bcur[i] = *(const bf16x8*)&Wp[lq * 1024 + ((wv + 4 * i) * 16 + lh) * 8];
    #pragma unroll
    for (int ks = 0; ks < 8; ++ks) {
        if (ks < 7) {
            #pragma unroll
            for (int i = 0; i < NTW; i++)
                bnxt[i] = *(const bf16x8*)&Wp[((ks + 1) * 4 + lq) * 1024 + ((wv + 4 * i) * 16 + lh) * 8];
        }
        bf16x8 a0 = *(const bf16x8*)&Alds[lh * 264 + ks * 32 + lq * 8];
        bf16x8 a1 = *(const bf16x8*)&Alds[(16 + lh) * 264 + ks * 32 + lq * 8];
        #pragma unroll
        for (int i = 0; i < NTW; i++) {
            acc[0][i] = __builtin_amdgcn_mfma_f32_16x16x32_bf16(a0, bcur[i], acc[0][i], 0, 0, 0);
            acc[1][i] = __builtin_amdgcn_mfma_f32_16x16x32_bf16(a1, bcur[i], acc[1][i], 0, 0, 0);
        }
        #pragma unroll
        for (int i = 0; i < NTW; i++) bcur[i] = bnxt[i];
    }
    __syncthreads();   // A reads done before Alds reuse as relu stash
    float* outF = (float*)outh;
    unsigned short* outB = (unsigned short*)outh;
    #pragma unroll
    for (int rt = 0; rt < 2; ++rt)
        #pragma unroll
        for (int i = 0; i < NTW; i++)
            #pragma unroll
            for (int j = 0; j < 4; j++) {
                int rl = rt * 16 + lq * 4 + j;
                int r = row0 + rl;
                int c = (wv + 4 * i) * 16 + lh;
                float v = acc[rt][i][j] + bias[c];
                Alds[rl * 264 + c] = f2bf(fmaxf(v, 0.f));
                if (r < nrows) {
                    if (xf32) __builtin_nontemporal_store(v, &outF[(size_t)r * 128 + c]);
                    else      outB[(size_t)r * 128 + c] = f2bf(v);
                }
            }
    __syncthreads();
    {   // repack relu bf16 -> fp8, coalesced u32x4
        int r = tid >> 3, c0 = (tid & 7) * 16;
        int rg = row0 + r;
        if (rg < nrows) {
            u32x4 va = *(u32x4*)&Alds[r * 264 + c0];
            u32x4 vb = *(u32x4*)&Alds[r * 264 + c0 + 8];
            u32x4 q;
            unsigned int w;
            w = 0;
            w = (unsigned int)__builtin_amdgcn_cvt_pk_fp8_f32(
                    bf2f((unsigned short)va.x), bf2f((unsigned short)(va.x >> 16)), (int)w, false);
            w = (unsigned int)__builtin_amdgcn_cvt_pk_fp8_f32(
                    bf2f((unsigned short)va.y), bf2f((unsigned short)(va.y >> 16)), (int)w, true);
            q.x = w;
            w = 0;
            w = (unsigned int)__builtin_amdgcn_cvt_pk_fp8_f32(
                    bf2f((unsigned short)va.z), bf2f((unsigned short)(va.z >> 16)), (int)w, false);
            w = (unsigned int)__builtin_amdgcn_cvt_pk_fp8_f32(
                    bf2f((unsigned short)va.w), bf2f((unsigned short)(va.w >> 16)), (int)w, true);
            q.y = w;
            w = 0;
            w = (unsigned int)__builtin_amdgcn_cvt_pk_fp8_f32(
                    bf2f((unsigned short)vb.x), bf2f((unsigned short)(vb.x >> 16)), (int)w, false);
            w = (unsigned int)__builtin_amdgcn_cvt_pk_fp8_f32(
                    bf2f((unsigned short)vb.y), bf2f((unsigned short)(vb.y >> 16)), (int)w, true);
            q.z = w;
            w = 0;
            w = (unsigned int)__builtin_amdgcn_cvt_pk_fp8_f32(
                    bf2f((unsigned short)vb.z), bf2f((unsigned short)(vb.z >> 16)), (int)w, false);
            w = (unsigned int)__builtin_amdgcn_cvt_pk_fp8_f32(
                    bf2f((unsigned short)vb.w), bf2f((unsigned short)(vb.w >> 16)), (int)w, true);
            q.w = w;
            *(u32x4*)&xemb8[(size_t)rg * 32 + (tid & 7) * 4] = q;
        }
    }
}

// ---------------------------------------------------------------------------
// Fused agg+GEMM2 (16 rows/block) + log_softmax: wave wv gathers nodes
// row0+wv*4..+3 from xemb8 into the A-tile; self-term decoded from xemb8.
// 2-deep B prefetch, register-space softmax epilogue, plain stores.
// ---------------------------------------------------------------------------
template <typename IT>
__global__ __launch_bounds__(256) void k_ag2(
    const unsigned int* __restrict__ xemb8,
    const int* __restrict__ rowptr, const int* __restrict__ aux,
    const int* __restrict__ deg, const IT* __restrict__ adj,
    const unsigned int* __restrict__ xprobe,
    const unsigned short* __restrict__ Wp,
    const float* __restrict__ bias, void* __restrict__ outbase, int nrows)
{
    constexpr int NTW = 5;
    __shared__ __align__(16) unsigned short Alds[16 * 264];
    __shared__ float redM[4][16];
    __shared__ float redS[4][16];
    int tid = threadIdx.x;
    int row0 = blockIdx.x * 16;
    int xf32 = probe_f32(xprobe);
    {   // stage self-term (cols 128..255) from xemb8
        int r = tid >> 4, c0 = (tid & 15) * 8;
        int rg = row0 + r; if (rg >= nrows) rg = nrows - 1;
        uint2 q = *(const uint2*)&xemb8[(size_t)rg * 32 + (c0 >> 2)];
        #pragma unroll
        for (int k = 0; k < 2; k++) {
            unsigned int w = (k == 0) ? q.x : q.y;
            f32x2 lo = __builtin_amdgcn_cvt_pk_f32_fp8((int)w, false);
            f32x2 hi = __builtin_amdgcn_cvt_pk_f32_fp8((int)w, true);
            unsigned int p0 = (unsigned int)f2bf(lo.x) | ((unsigned int)f2bf(lo.y) << 16);
            unsigned int p1 = (unsigned int)f2bf(hi.x) | ((unsigned int)f2bf(hi.y) << 16);
            *(unsigned int*)&Alds[r * 264 + 128 + c0 + k * 4]     = p0;
            *(unsigned int*)&Alds[r * 264 + 128 + c0 + k * 4 + 2] = p1;
        }
    }
    int lane = tid & 63, wv = tid >> 6, lh = lane & 15, lq = lane >> 4;
    {   // gather phase: wave wv aggregates its 4 rows into cols 0..127
        int h = lane >> 5, sl = lane & 31;
        for (int k = 0; k < 4; k++) {
            int rl = wv * 4 + k;
            int rg = row0 + rl; if (rg >= nrows) rg = nrows - 1;
            gather_mean_to_lds<IT>(xemb8, rowptr, aux, deg, adj, rg, h, sl,
                                   &Alds[rl * 264]);
        }
    }
    __syncthreads();
    f32x4 acc[NTW];
    #pragma unroll
    for (int b = 0; b < NTW; b++) acc[b] = f32x4{0.f, 0.f, 0.f, 0.f};
    bf16x8 bcur[NTW], bnxt[NTW];
    #pragma unroll
    for (int i = 0; i < NTW; i++)
        bcur[i] = *(const bf16x8*)&Wp[lq * 2560 + ((wv + 4 * i) * 16 + lh) * 8];
    #pragma unroll
    for (int ks = 0; ks < 8; ++ks) {
        if (ks < 7) {
            #pragma unroll
            for (int i = 0; i < NTW; i++)
                bnxt[i] = *(const bf16x8*)&Wp[((ks + 1) * 4 + lq) * 2560 + ((wv + 4 * i) * 16 + lh) * 8];
        }
        bf16x8 a0 = *(const bf16x8*)&Alds[lh * 264 + ks * 32 + lq * 8];
        #pragma unroll
        for (int i = 0; i < NTW; i++)
            acc[i] = __builtin_amdgcn_mfma_f32_16x16x32_bf16(a0, bcur[i], acc[i], 0, 0, 0);
        #pragma unroll
        for (int i = 0; i < NTW; i++) bcur[i] = bnxt[i];
    }
    #pragma unroll
    for (int i = 0; i < NTW; i++) {
        int col = (wv + 4 * i) * 16 + lh;
        float b = bias[col];
        #pragma unroll
        for (int j = 0; j < 4; j++) acc[i][j] += b;
    }
    float M[4];
    #pragma unroll
    for (int j = 0; j < 4; j++) {
        float m = -3.0e38f;
        #pragma unroll
        for (int i = 0; i < NTW; i++) {
            int col = (wv + 4 * i) * 16 + lh;
            if (col < 300) m = fmaxf(m, acc[i][j]);
        }
        m = fmaxf(m, __shfl_xor(m, 1, 16));
        m = fmaxf(m, __shfl_xor(m, 2, 16));
        m = fmaxf(m, __shfl_xor(m, 4, 16));
        m = fmaxf(m, __shfl_xor(m, 8, 16));
        M[j] = m;
    }
    if (lh == 0) {
        #pragma unroll
        for (int j = 0; j < 4; j++) redM[wv][lq * 4 + j] = M[j];
    }
    __syncthreads();
    #pragma unroll
    for (int j = 0; j < 4; j++) {
        int rl = lq * 4 + j;
        M[j] = fmaxf(fmaxf(redM[0][rl], redM[1][rl]),
                     fmaxf(redM[2][rl], redM[3][rl]));
    }
    float S[4];
    #pragma unroll
    for (int j = 0; j < 4; j++) {
        float s = 0.f;
        #pragma unroll
        for (int i = 0; i < NTW; i++) {
            int col = (wv + 4 * i) * 16 + lh;
            if (col < 300) s += __expf(acc[i][j] - M[j]);
        }
        s += __shfl_xor(s, 1, 16);
        s += __shfl_xor(s, 2, 16);
        s += __shfl_xor(s, 4, 16);
        s += __shfl_xor(s, 8, 16);
        S[j] = s;
    }
    if (lh == 0) {
        #pragma unroll
        for (int j = 0; j < 4; j++) redS[wv][lq * 4 + j] = S[j];
    }
    __syncthreads();
    float* out1F = (float*)outbase + (size_t)nrows * 128;
    unsigned short* out1B = (unsigned short*)outbase + (size_t)nrows * 128;
    #pragma unroll
    for (int j = 0; j < 4; j++) {
        int rl = lq * 4 + j;
        float Sall = (redS[0][rl] + redS[1][rl]) + (redS[2][rl] + redS[3][rl]);
        float L = M[j] + __logf(Sall);
        int rg = row0 + rl;
        if (rg < nrows) {
            #pragma unroll
            for (int i = 0; i < NTW; i++) {
                int col = (wv + 4 * i) * 16 + lh;
                if (col < 300) {
                    float v = acc[i][j] - L;
                    if (xf32) out1F[(size_t)rg * 300 + col] = v;
                    else      out1B[(size_t)rg * 300 + col] = f2bf(v);
                }
            }
        }
    }
}

// ---------------------------------------------------------------------------
extern "C" void kernel_launch(void* const* d_in, const int* in_sizes, int n_in,
                              void* d_out, int out_size, void* d_ws, size_t ws_size,
                              hipStream_t stream)
{
    const void* x     = d_in[0];
    const int*  ei    = (const int*)d_in[1];
    const void* Wl    = d_in[2];
    const void* bl    = d_in[3];
    const void* Wr    = d_in[4];
    const void* Wsk   = d_in[5];
    const void* bsk   = d_in[6];
    const void* gamma = d_in[7];
    const void* beta  = d_in[8];
    const void* rmean = d_in[9];
    const void* rvar  = d_in[10];
    const void* Wlo   = d_in[11];
    const void* blo   = d_in[12];
    const void* Wro   = d_in[13];

    int N = in_sizes[0] / 128;
    int E = in_sizes[1] / 2;
    long nelem = (long)N * 128;
    bool idx16 = (N <= 65535);

    char* ws = (char*)d_ws;
    size_t off = 0;
    unsigned short* xbf   = (unsigned short*)(ws + off); off += (size_t)N * 128 * 2;
    unsigned int* x8      = (unsigned int*)(ws + off);   off += (size_t)N * 128;
    unsigned int* xemb8   = (unsigned int*)(ws + off);   off += (size_t)N * 128;
    off = (off + 255) & ~(size_t)255;
    int* deg    = (int*)(ws + off);           off += (size_t)N * 4;
    int* scnt   = (int*)(ws + off);           off += 256;   // zeroed with deg
    int* rowptr = (int*)(ws + off);           off += (size_t)N * 4;
    int* rank   = (int*)(ws + off);           off += (size_t)E * 4;
    unsigned int* ds32 = (unsigned int*)(ws + off); off += (size_t)E * 4;
    int* aux    = (int*)(ws + off);           off += 256;
    void* adjv  = (void*)(ws + off);          off += (size_t)E * 4;
    off = (off + 255) & ~(size_t)255;
    unsigned short* W1p = (unsigned short*)(ws + off);  off += 32768 * 2;
    unsigned short* W2p = (unsigned short*)(ws + off);  off += 81920 * 2;
    float* bias1 = (float*)(ws + off);        off += 512;
    float* bias2 = (float*)(ws + off);        off += 1280;

    int egrid  = (E + 255) / 256;
    int sblk   = (N + 1023) / 1024;
    int g1grid = (N + 31) / 32;
    int g2grid = (N + 15) / 16;
    int tgrid  = (int)((nelem / 8 + 255) / 256);

    const unsigned int* xprobe = (const unsigned int*)x;

    // deg + scnt must be zero before k_front / k_scan.
    hipMemsetAsync(deg, 0, (size_t)N * 4 + 256, stream);

    // rank || tobf interleaved by parity, fold at the tail.
    k_front<<<egrid + tgrid + 449, 256, 0, stream>>>(
        ei, deg, rank, ds32, E, N, idx16 ? 1 : 0, egrid,
        x, xbf, x8, nelem, tgrid,
        Wl, Wr, Wsk, gamma, rvar, bl, bsk, rmean, beta, Wlo, blo, Wro,
        W1p, W2p, bias1, bias2);

    // fused two-level scan (last block does the aux fixup).
    k_scan<<<sblk, 256, 0, stream>>>(deg, rowptr, aux, scnt, N, sblk);

    if (idx16) {
        unsigned short* adj = (unsigned short*)adjv;
        k_place16<<<egrid, 256, 0, stream>>>(ds32, rowptr, aux, rank, adj, E, N);
        k_ag1<unsigned short><<<g1grid, 256, 0, stream>>>(
            x8, rowptr, aux, deg, adj, xbf, xprobe, W1p, bias1, d_out, xemb8, N);
        k_ag2<unsigned short><<<g2grid, 256, 0, stream>>>(
            xemb8, rowptr, aux, deg, adj, xprobe, W2p, bias2, d_out, N);
    } else {
        int* adj = (int*)adjv;
        k_place32<<<egrid, 256, 0, stream>>>(ei, rowptr, aux, rank, adj, E, N);
        k_ag1<int><<<g1grid, 256, 0, stream>>>(
            x8, rowptr, aux, deg, adj, xbf, xprobe, W1p, bias1, d_out, xemb8, N);
        k_ag2<int><<<g2grid, 256, 0, stream>>>(
            xemb8, rowptr, aux, deg, adj, xprobe, W2p, bias2, d_out, N);
    }
}

// Round 17
// 159.548 us; speedup vs baseline: 1.0783x; 1.0783x over previous
//
#include <hip/hip_runtime.h>

typedef __attribute__((__ext_vector_type__(8))) __bf16 bf16x8;
typedef __attribute__((__ext_vector_type__(4))) float f32x4;
typedef __attribute__((__ext_vector_type__(2))) float f32x2;
typedef __attribute__((__ext_vector_type__(4))) unsigned int u32x4;

__device__ __forceinline__ float bf2f(unsigned short u) {
    return __uint_as_float(((unsigned int)u) << 16);
}
__device__ __forceinline__ unsigned short f2bf(float f) {
    unsigned int u = __float_as_uint(f);
    u += 0x7FFFu + ((u >> 16) & 1u);   // RNE
    return (unsigned short)(u >> 16);
}

// ---------------------------------------------------------------------------
// Per-wave dtype probes (validated rounds 9-15).
// ---------------------------------------------------------------------------
__device__ __forceinline__ bool low_short_is_bf16like(unsigned int w) {
    unsigned int lo = w & 0xFFFFu;
    if (lo == 0u || lo == 0x8000u) return true;
    unsigned int e = (lo >> 7) & 0xFFu;
    return (e >= 0x6Cu && e <= 0x8Cu);
}
__device__ __forceinline__ int probe_f32(const unsigned int* __restrict__ p) {
    int t = threadIdx.x & 63;
    int cnt = __popcll(__ballot(low_short_is_bf16like(p[t])));
    return (cnt < 32) ? 1 : 0;
}
__device__ __forceinline__ int probe_e64(const unsigned int* __restrict__ ei) {
    int t = threadIdx.x & 63;
    unsigned int o1 = ei[2 * t + 1];
    unsigned int o2 = ei[2 * t + 129];
    return __all((o1 == 0u) && (o2 == 0u)) ? 1 : 0;
}

// ---------------------------------------------------------------------------
// k_front: rank || tobf interleaved by block parity, fold at the tail.
// (validated round 14)
// ---------------------------------------------------------------------------
__device__ __forceinline__ void front_rank(
    int blk, int t, const int* __restrict__ ei, int* __restrict__ deg,
    int* __restrict__ rank, unsigned int* __restrict__ ds32,
    int E, int nnodes, int pack)
{
    int e64 = probe_e64((const unsigned int*)ei);
    int e = blk * 256 + t;
    if (e >= E) return;
    int s, d;
    if (e64) { s = ei[2 * e]; d = ei[2 * (E + e)]; }
    else     { s = ei[e];     d = ei[E + e]; }
    if ((unsigned)s >= (unsigned)nnodes) s = 0;
    int r = 0;
    if ((unsigned)d < (unsigned)nnodes) r = atomicAdd(&deg[d], 1);
    rank[e] = r;
    if (pack) ds32[e] = (((unsigned int)d & 0xFFFFu) << 16) | ((unsigned int)s & 0xFFFFu);
}

__device__ __forceinline__ void front_tobf(
    int blk, int t, const void* __restrict__ xv,
    unsigned short* __restrict__ xbf, unsigned int* __restrict__ x8, long nelem)
{
    int xf32 = probe_f32((const unsigned int*)xv);
    long i = ((long)blk * 256 + t) * 8;
    if (i >= nelem) return;
    float f[8];
    if (xf32) {
        const float4* p = (const float4*)((const float*)xv + i);
        float4 v0 = p[0], v1 = p[1];
        f[0] = v0.x; f[1] = v0.y; f[2] = v0.z; f[3] = v0.w;
        f[4] = v1.x; f[5] = v1.y; f[6] = v1.z; f[7] = v1.w;
        u32x4 o;
        o.x = (unsigned int)f2bf(f[0]) | ((unsigned int)f2bf(f[1]) << 16);
        o.y = (unsigned int)f2bf(f[2]) | ((unsigned int)f2bf(f[3]) << 16);
        o.z = (unsigned int)f2bf(f[4]) | ((unsigned int)f2bf(f[5]) << 16);
        o.w = (unsigned int)f2bf(f[6]) | ((unsigned int)f2bf(f[7]) << 16);
        *(u32x4*)&xbf[i] = o;
    } else {
        u32x4 v = *(const u32x4*)((const unsigned short*)xv + i);
        *(u32x4*)&xbf[i] = v;
        f[0] = bf2f((unsigned short)v.x); f[1] = bf2f((unsigned short)(v.x >> 16));
        f[2] = bf2f((unsigned short)v.y); f[3] = bf2f((unsigned short)(v.y >> 16));
        f[4] = bf2f((unsigned short)v.z); f[5] = bf2f((unsigned short)(v.z >> 16));
        f[6] = bf2f((unsigned short)v.w); f[7] = bf2f((unsigned short)(v.w >> 16));
    }
    unsigned int q0 = 0, q1 = 0;
    q0 = (unsigned int)__builtin_amdgcn_cvt_pk_fp8_f32(f[0], f[1], (int)q0, false);
    q0 = (unsigned int)__builtin_amdgcn_cvt_pk_fp8_f32(f[2], f[3], (int)q0, true);
    q1 = (unsigned int)__builtin_amdgcn_cvt_pk_fp8_f32(f[4], f[5], (int)q1, false);
    q1 = (unsigned int)__builtin_amdgcn_cvt_pk_fp8_f32(f[6], f[7], (int)q1, true);
    uint2 q; q.x = q0; q.y = q1;
    *(uint2*)&x8[i >> 2] = q;
}

__global__ __launch_bounds__(256) void k_front(
    const int* __restrict__ ei, int* __restrict__ deg, int* __restrict__ rank,
    unsigned int* __restrict__ ds32, int E, int nnodes, int pack, int egrid,
    const void* __restrict__ xv, unsigned short* __restrict__ xbf,
    unsigned int* __restrict__ x8, long nelem, int tgrid,
    const void* __restrict__ Wl, const void* __restrict__ Wr,
    const void* __restrict__ Wsk, const void* __restrict__ gamma,
    const void* __restrict__ rvar, const void* __restrict__ bl,
    const void* __restrict__ bsk, const void* __restrict__ rmean,
    const void* __restrict__ beta, const void* __restrict__ Wlo,
    const void* __restrict__ blo, const void* __restrict__ Wro,
    unsigned short* __restrict__ W1p, unsigned short* __restrict__ W2p,
    float* __restrict__ bias1, float* __restrict__ bias2)
{
    int blk = blockIdx.x, t = threadIdx.x;
    int mn = (egrid < tgrid) ? egrid : tgrid;
    int m2 = 2 * mn;
    if (blk < m2) {
        if (blk & 1) front_tobf(blk >> 1, t, xv, xbf, x8, nelem);
        else         front_rank(blk >> 1, t, ei, deg, rank, ds32, E, nnodes, pack);
        return;
    }
    if (blk < egrid + tgrid) {
        int r = blk - m2;
        if (egrid > tgrid) front_rank(mn + r, t, ei, deg, rank, ds32, E, nnodes, pack);
        else               front_tobf(mn + r, t, xv, xbf, x8, nelem);
        return;
    }
    // ---- fold ----
    int wf32 = probe_f32((const unsigned int*)Wl);
    int b = blk - egrid - tgrid;
    if (b < 128) {
        int idx = b * 256 + t;
        int kb = idx >> 10, c = (idx >> 3) & 127, k7 = idx & 7;
        int k = kb * 8 + k7;
        float g, rv, w;
        if (wf32) {
            g  = ((const float*)gamma)[c];
            rv = ((const float*)rvar)[c];
            if (k < 128) w = ((const float*)Wl)[k * 128 + c];
            else { int kk = k - 128;
                   w = ((const float*)Wr)[kk * 128 + c] + ((const float*)Wsk)[kk * 128 + c]; }
        } else {
            g  = bf2f(((const unsigned short*)gamma)[c]);
            rv = bf2f(((const unsigned short*)rvar)[c]);
            if (k < 128) w = bf2f(((const unsigned short*)Wl)[k * 128 + c]);
            else { int kk = k - 128;
                   w = bf2f(((const unsigned short*)Wr)[kk * 128 + c]) +
                       bf2f(((const unsigned short*)Wsk)[kk * 128 + c]); }
        }
        float s = g * rsqrtf(rv + 1e-5f);
        W1p[idx] = f2bf(w * s);
    } else if (b < 448) {
        int idx = (b - 128) * 256 + t;
        int kb = idx / 2560;
        int rem = idx - kb * 2560;
        int c = rem >> 3, k7 = idx & 7;
        int k = kb * 8 + k7;
        float w = 0.f;
        if (c < 300) {
            if (wf32)
                w = (k < 128) ? ((const float*)Wlo)[k * 300 + c]
                              : ((const float*)Wro)[(k - 128) * 300 + c];
            else
                w = (k < 128) ? bf2f(((const unsigned short*)Wlo)[k * 300 + c])
                              : bf2f(((const unsigned short*)Wro)[(k - 128) * 300 + c]);
        }
        W2p[idx] = f2bf(w);
    } else {
        if (t < 128) {
            float g, rv, b1, b2, rm, be;
            if (wf32) {
                g = ((const float*)gamma)[t]; rv = ((const float*)rvar)[t];
                b1 = ((const float*)bl)[t];   b2 = ((const float*)bsk)[t];
                rm = ((const float*)rmean)[t]; be = ((const float*)beta)[t];
            } else {
                g = bf2f(((const unsigned short*)gamma)[t]); rv = bf2f(((const unsigned short*)rvar)[t]);
                b1 = bf2f(((const unsigned short*)bl)[t]);   b2 = bf2f(((const unsigned short*)bsk)[t]);
                rm = bf2f(((const unsigned short*)rmean)[t]); be = bf2f(((const unsigned short*)beta)[t]);
            }
            float s = g * rsqrtf(rv + 1e-5f);
            bias1[t] = (b1 + b2 - rm) * s + be;
        }
        for (int c = t; c < 320; c += 256) {
            float v = 0.f;
            if (c < 300)
                v = wf32 ? ((const float*)blo)[c] : bf2f(((const unsigned short*)blo)[c]);
            bias2[c] = v;
        }
    }
}

// ---------------------------------------------------------------------------
// Fused two-level scan (validated round 14).
// ---------------------------------------------------------------------------
__global__ __launch_bounds__(256) void k_scan(
    const int* __restrict__ deg, int* __restrict__ rowptr,
    int* __restrict__ aux, int* __restrict__ scnt, int n, int nblk)
{
    __shared__ int wsum[4];
    __shared__ int lastflag;
    int t = threadIdx.x, blk = blockIdx.x;
    int base = blk * 1024 + t * 4;
    int v[4];
    int s = 0;
    #pragma unroll
    for (int i = 0; i < 4; i++) { int idx = base + i; v[i] = (idx < n) ? deg[idx] : 0; s += v[i]; }
    int lane = t & 63, wv = t >> 6;
    int inc = s;
    #pragma unroll
    for (int off = 1; off < 64; off <<= 1) {
        int u = __shfl_up(inc, off);
        if (lane >= off) inc += u;
    }
    if (lane == 63) wsum[wv] = inc;
    __syncthreads();
    int woff = 0;
    if (wv >= 1) woff += wsum[0];
    if (wv >= 2) woff += wsum[1];
    if (wv >= 3) woff += wsum[2];
    int exc = woff + inc - s;
    #pragma unroll
    for (int i = 0; i < 4; i++) { int idx = base + i; if (idx < n) rowptr[idx] = exc; exc += v[i]; }
    if (t == 255) {
        aux[blk] = woff + inc;
        __threadfence();
        int prev = atomicAdd(scnt, 1);
        lastflag = (prev == nblk - 1) ? 1 : 0;
    }
    __syncthreads();
    if (lastflag && t < 64) {
        __threadfence();
        int carry = 0;
        for (int b2 = 0; b2 < nblk; b2 += 64) {
            int idx = b2 + t;
            int av = (idx < nblk) ? aux[idx] : 0;
            int inc2 = av;
            #pragma unroll
            for (int off = 1; off < 64; off <<= 1) {
                int u = __shfl_up(inc2, off);
                if (t >= off) inc2 += u;
            }
            if (idx < nblk) aux[idx] = carry + inc2 - av;   // exclusive
            carry += __shfl(inc2, 63);
        }
    }
}

__global__ __launch_bounds__(256) void k_place16(
    const unsigned int* __restrict__ ds32,
    const int* __restrict__ rowptr, const int* __restrict__ aux,
    const int* __restrict__ rank,
    unsigned short* __restrict__ adj, int E, int nnodes)
{
    int e = blockIdx.x * 256 + threadIdx.x;
    if (e >= E) return;
    unsigned int ds = ds32[e];
    int d = (int)(ds >> 16);
    unsigned short s = (unsigned short)(ds & 0xFFFFu);
    if (d >= nnodes) return;
    adj[rowptr[d] + aux[d >> 10] + rank[e]] = s;
}

__global__ __launch_bounds__(256) void k_place32(
    const int* __restrict__ ei,
    const int* __restrict__ rowptr, const int* __restrict__ aux,
    const int* __restrict__ rank,
    int* __restrict__ adj, int E, int nnodes)
{
    int e64 = probe_e64((const unsigned int*)ei);
    int e = blockIdx.x * 256 + threadIdx.x;
    if (e >= E) return;
    int s, d;
    if (e64) { s = ei[2 * e]; d = ei[2 * (E + e)]; }
    else     { s = ei[e];     d = ei[E + e]; }
    if ((unsigned)d >= (unsigned)nnodes) return;
    if ((unsigned)s >= (unsigned)nnodes) s = 0;
    adj[rowptr[d] + aux[d >> 10] + rank[e]] = s;
}

// ---------------------------------------------------------------------------
// Gather-mean over fp8 rows (validated rounds 10-15; one wave per node,
// 16 edges in flight).
// ---------------------------------------------------------------------------
template <typename IT>
__global__ __launch_bounds__(256) void k_agg(
    const unsigned int* __restrict__ x8,
    const int* __restrict__ rowptr, const int* __restrict__ aux,
    const int* __restrict__ deg,
    const IT* __restrict__ adj, unsigned short* __restrict__ meanB, int n)
{
    int wid = (blockIdx.x * 256 + threadIdx.x) >> 6;
    if (wid >= n) return;
    int lane = threadIdx.x & 63;
    int h  = lane >> 5;
    int sl = lane & 31;
    int start = rowptr[wid] + aux[wid >> 10];
    int dc = deg[wid];
    float acc[4][4];
    #pragma unroll
    for (int u = 0; u < 4; u++)
        #pragma unroll
        for (int c = 0; c < 4; c++) acc[u][c] = 0.f;
    int i = 0;
    for (; i + 15 < dc; i += 16) {
        int e[8]; unsigned int p[8];
        #pragma unroll
        for (int u = 0; u < 8; u++) e[u] = (int)adj[start + i + 2 * u + h];
        #pragma unroll
        for (int u = 0; u < 8; u++) p[u] = x8[(size_t)e[u] * 32 + sl];
        #pragma unroll
        for (int u = 0; u < 8; u++) {
            f32x2 lo = __builtin_amdgcn_cvt_pk_f32_fp8((int)p[u], false);
            f32x2 hi = __builtin_amdgcn_cvt_pk_f32_fp8((int)p[u], true);
            acc[u & 3][0] += lo.x; acc[u & 3][1] += lo.y;
            acc[u & 3][2] += hi.x; acc[u & 3][3] += hi.y;
        }
    }
    if (i + 7 < dc) {
        int e[4]; unsigned int p[4];
        #pragma unroll
        for (int u = 0; u < 4; u++) e[u] = (int)adj[start + i + 2 * u + h];
        #pragma unroll
        for (int u = 0; u < 4; u++) p[u] = x8[(size_t)e[u] * 32 + sl];
        #pragma unroll
        for (int u = 0; u < 4; u++) {
            f32x2 lo = __builtin_amdgcn_cvt_pk_f32_fp8((int)p[u], false);
            f32x2 hi = __builtin_amdgcn_cvt_pk_f32_fp8((int)p[u], true);
            acc[u][0] += lo.x; acc[u][1] += lo.y;
            acc[u][2] += hi.x; acc[u][3] += hi.y;
        }
        i += 8;
    }
    for (; i + h < dc; i += 2) {
        int e0 = (int)adj[start + i + h];
        unsigned int p0 = x8[(size_t)e0 * 32 + sl];
        f32x2 lo = __builtin_amdgcn_cvt_pk_f32_fp8((int)p0, false);
        f32x2 hi = __builtin_amdgcn_cvt_pk_f32_fp8((int)p0, true);
        acc[0][0] += lo.x; acc[0][1] += lo.y; acc[0][2] += hi.x; acc[0][3] += hi.y;
    }
    float t0 = (acc[0][0] + acc[1][0]) + (acc[2][0] + acc[3][0]);
    float t1 = (acc[0][1] + acc[1][1]) + (acc[2][1] + acc[3][1]);
    float t2 = (acc[0][2] + acc[1][2]) + (acc[2][2] + acc[3][2]);
    float t3 = (acc[0][3] + acc[1][3]) + (acc[2][3] + acc[3][3]);
    t0 += __shfl_xor(t0, 32);
    t1 += __shfl_xor(t1, 32);
    t2 += __shfl_xor(t2, 32);
    t3 += __shfl_xor(t3, 32);
    if (h == 0) {
        float inv = 1.f / fmaxf((float)dc, 1.f);
        uint2 o;
        o.x = (unsigned int)f2bf(t0 * inv) | ((unsigned int)f2bf(t1 * inv) << 16);
        o.y = (unsigned int)f2bf(t2 * inv) | ((unsigned int)f2bf(t3 * inv) << 16);
        *(uint2*)&meanB[(size_t)wid * 128 + sl * 4] = o;
    }
}

// ---------------------------------------------------------------------------
// GEMM1 (32 rows/block): h = [mean | xbf] @ W1p + bias1. NT h-store, fused
// xemb8 repack, 2-deep B prefetch. (validated rounds 12-15)
// ---------------------------------------------------------------------------
__global__ __launch_bounds__(256) void k_gemm1(
    const unsigned short* __restrict__ meanB,
    const unsigned short* __restrict__ xbf, const unsigned int* __restrict__ xprobe,
    const unsigned short* __restrict__ Wp,
    const float* __restrict__ bias, void* __restrict__ outh,
    unsigned int* __restrict__ xemb8, int nrows)
{
    constexpr int NTW = 2;
    __shared__ __align__(16) unsigned short Alds[32 * 264];
    int tid = threadIdx.x;
    int row0 = blockIdx.x * 32;
    int xf32 = probe_f32(xprobe);
    {
        int r = tid >> 3, c0 = (tid & 7) * 16;
        int rg = row0 + r; if (rg >= nrows) rg = nrows - 1;
        const u32x4* mp = (const u32x4*)(meanB + (size_t)rg * 128 + c0);
        *(u32x4*)&Alds[r * 264 + c0]     = mp[0];
        *(u32x4*)&Alds[r * 264 + c0 + 8] = mp[1];
        const u32x4* xp = (const u32x4*)(xbf + (size_t)rg * 128 + c0);
        *(u32x4*)&Alds[r * 264 + 128 + c0]     = xp[0];
        *(u32x4*)&Alds[r * 264 + 128 + c0 + 8] = xp[1];
    }
    __syncthreads();
    f32x4 acc[2][NTW];
    #pragma unroll
    for (int a = 0; a < 2; a++)
        #pragma unroll
        for (int b = 0; b < NTW; b++) acc[a][b] = f32x4{0.f, 0.f, 0.f, 0.f};
    int lane = tid & 63, wv = tid >> 6, lh = lane & 15, lq = lane >> 4;
    bf16x8 bcur[NTW], bnxt[NTW];
    #pragma unroll
    for (int i = 0; i < NTW; i++)
        bcur[i] = *(const bf16x8*)&Wp[lq * 1024 + ((wv + 4 * i) * 16 + lh) * 8];
    #pragma unroll
    for (int ks = 0; ks < 8; ++ks) {
        if (ks < 7) {
            #pragma unroll
            for (int i = 0; i < NTW; i++)
                bnxt[i] = *(const bf16x8*)&Wp[((ks + 1) * 4 + lq) * 1024 + ((wv + 4 * i) * 16 + lh) * 8];
        }
        bf16x8 a0 = *(const bf16x8*)&Alds[lh * 264 + ks * 32 + lq * 8];
        bf16x8 a1 = *(const bf16x8*)&Alds[(16 + lh) * 264 + ks * 32 + lq * 8];
        #pragma unroll
        for (int i = 0; i < NTW; i++) {
            acc[0][i] = __builtin_amdgcn_mfma_f32_16x16x32_bf16(a0, bcur[i], acc[0][i], 0, 0, 0);
            acc[1][i] = __builtin_amdgcn_mfma_f32_16x16x32_bf16(a1, bcur[i], acc[1][i], 0, 0, 0);
        }
        #pragma unroll
        for (int i = 0; i < NTW; i++) bcur[i] = bnxt[i];
    }
    __syncthreads();
    float* outF = (float*)outh;
    unsigned short* outB = (unsigned short*)outh;
    #pragma unroll
    for (int rt = 0; rt < 2; ++rt)
        #pragma unroll
        for (int i = 0; i < NTW; i++)
            #pragma unroll
            for (int j = 0; j < 4; j++) {
                int rl = rt * 16 + lq * 4 + j;
                int r = row0 + rl;
                int c = (wv + 4 * i) * 16 + lh;
                float v = acc[rt][i][j] + bias[c];
                Alds[rl * 264 + c] = f2bf(fmaxf(v, 0.f));
                if (r < nrows) {
                    if (xf32) __builtin_nontemporal_store(v, &outF[(size_t)r * 128 + c]);
                    else      outB[(size_t)r * 128 + c] = f2bf(v);
                }
            }
    __syncthreads();
    {
        int r = tid >> 3, c0 = (tid & 7) * 16;
        int rg = row0 + r;
        if (rg < nrows) {
            u32x4 va = *(u32x4*)&Alds[r * 264 + c0];
            u32x4 vb = *(u32x4*)&Alds[r * 264 + c0 + 8];
            u32x4 q;
            unsigned int w;
            w = 0;
            w = (unsigned int)__builtin_amdgcn_cvt_pk_fp8_f32(
                    bf2f((unsigned short)va.x), bf2f((unsigned short)(va.x >> 16)), (int)w, false);
            w = (unsigned int)__builtin_amdgcn_cvt_pk_fp8_f32(
                    bf2f((unsigned short)va.y), bf2f((unsigned short)(va.y >> 16)), (int)w, true);
            q.x = w;
            w = 0;
            w = (unsigned int)__builtin_amdgcn_cvt_pk_fp8_f32(
                    bf2f((unsigned short)va.z), bf2f((unsigned short)(va.z >> 16)), (int)w, false);
            w = (unsigned int)__builtin_amdgcn_cvt_pk_fp8_f32(
                    bf2f((unsigned short)va.w), bf2f((unsigned short)(va.w >> 16)), (int)w, true);
            q.y = w;
            w = 0;
            w = (unsigned int)__builtin_amdgcn_cvt_pk_fp8_f32(
                    bf2f((unsigned short)vb.x), bf2f((unsigned short)(vb.x >> 16)), (int)w, false);
            w = (unsigned int)__builtin_amdgcn_cvt_pk_fp8_f32(
                    bf2f((unsigned short)vb.y), bf2f((unsigned short)(vb.y >> 16)), (int)w, true);
            q.z = w;
            w = 0;
            w = (unsigned int)__builtin_amdgcn_cvt_pk_fp8_f32(
                    bf2f((unsigned short)vb.z), bf2f((unsigned short)(vb.z >> 16)), (int)w, false);
            w = (unsigned int)__builtin_amdgcn_cvt_pk_fp8_f32(
                    bf2f((unsigned short)vb.w), bf2f((unsigned short)(vb.w >> 16)), (int)w, true);
            q.w = w;
            *(u32x4*)&xemb8[(size_t)rg * 32 + (tid & 7) * 4] = q;
        }
    }
}

// ---------------------------------------------------------------------------
// GEMM2 (16 rows/block) + fused log_softmax. 3125 blocks for latency hiding
// via occupancy. A self-term from xemb8, 2-deep B prefetch, plain stores.
// (validated round 15)
// ---------------------------------------------------------------------------
__global__ __launch_bounds__(256) void k_gemm2(
    const unsigned short* __restrict__ meanB,
    const unsigned int* __restrict__ xemb8, const unsigned int* __restrict__ xprobe,
    const unsigned short* __restrict__ Wp,
    const float* __restrict__ bias, void* __restrict__ outbase, int nrows)
{
    constexpr int NTW = 5;
    __shared__ __align__(16) unsigned short Alds[16 * 264];
    __shared__ float redM[4][16];
    __shared__ float redS[4][16];
    int tid = threadIdx.x;
    int row0 = blockIdx.x * 16;
    int xf32 = probe_f32(xprobe);
    {   // stage A: 16 threads/row; each loads 8 bf16 of mean + 8 (from fp8) of xemb
        int r = tid >> 4, c0 = (tid & 15) * 8;
        int rg = row0 + r; if (rg >= nrows) rg = nrows - 1;
        *(u32x4*)&Alds[r * 264 + c0] = *(const u32x4*)(meanB + (size_t)rg * 128 + c0);
        uint2 q = *(const uint2*)&xemb8[(size_t)rg * 32 + (c0 >> 2)];
        #pragma unroll
        for (int k = 0; k < 2; k++) {
            unsigned int w = (k == 0) ? q.x : q.y;
            f32x2 lo = __builtin_amdgcn_cvt_pk_f32_fp8((int)w, false);
            f32x2 hi = __builtin_amdgcn_cvt_pk_f32_fp8((int)w, true);
            unsigned int p0 = (unsigned int)f2bf(lo.x) | ((unsigned int)f2bf(lo.y) << 16);
            unsigned int p1 = (unsigned int)f2bf(hi.x) | ((unsigned int)f2bf(hi.y) << 16);
            *(unsigned int*)&Alds[r * 264 + 128 + c0 + k * 4]     = p0;
            *(unsigned int*)&Alds[r * 264 + 128 + c0 + k * 4 + 2] = p1;
        }
    }
    __syncthreads();
    f32x4 acc[NTW];
    #pragma unroll
    for (int b = 0; b < NTW; b++) acc[b] = f32x4{0.f, 0.f, 0.f, 0.f};
    int lane = tid & 63, wv = tid >> 6, lh = lane & 15, lq = lane >> 4;
    bf16x8 bcur[NTW], bnxt[NTW];
    #pragma unroll
    for (int i = 0; i < NTW; i++)
        bcur[i] = *(const bf16x8*)&Wp[lq * 2560 + ((wv + 4 * i) * 16 + lh) * 8];
    #pragma unroll
    for (int ks = 0; ks < 8; ++ks) {
        if (ks < 7) {
            #pragma unroll
            for (int i = 0; i < NTW; i++)
                bnxt[i] = *(const bf16x8*)&Wp[((ks + 1) * 4 + lq) * 2560 + ((wv + 4 * i) * 16 + lh) * 8];
        }
        bf16x8 a0 = *(const bf16x8*)&Alds[lh * 264 + ks * 32 + lq * 8];
        #pragma unroll
        for (int i = 0; i < NTW; i++)
            acc[i] = __builtin_amdgcn_mfma_f32_16x16x32_bf16(a0, bcur[i], acc[i], 0, 0, 0);
        #pragma unroll
        for (int i = 0; i < NTW; i++) bcur[i] = bnxt[i];
    }
    #pragma unroll
    for (int i = 0; i < NTW; i++) {
        int col = (wv + 4 * i) * 16 + lh;
        float b = bias[col];
        #pragma unroll
        for (int j = 0; j < 4; j++) acc[i][j] += b;
    }
    float M[4];
    #pragma unroll
    for (int j = 0; j < 4; j++) {
        float m = -3.0e38f;
        #pragma unroll
        for (int i = 0; i < NTW; i++) {
            int col = (wv + 4 * i) * 16 + lh;
            if (col < 300) m = fmaxf(m, acc[i][j]);
        }
        m = fmaxf(m, __shfl_xor(m, 1, 16));
        m = fmaxf(m, __shfl_xor(m, 2, 16));
        m = fmaxf(m, __shfl_xor(m, 4, 16));
        m = fmaxf(m, __shfl_xor(m, 8, 16));
        M[j] = m;
    }
    if (lh == 0) {
        #pragma unroll
        for (int j = 0; j < 4; j++) redM[wv][lq * 4 + j] = M[j];
    }
    __syncthreads();
    #pragma unroll
    for (int j = 0; j < 4; j++) {
        int rl = lq * 4 + j;
        M[j] = fmaxf(fmaxf(redM[0][rl], redM[1][rl]),
                     fmaxf(redM[2][rl], redM[3][rl]));
    }
    float S[4];
    #pragma unroll
    for (int j = 0; j < 4; j++) {
        float s = 0.f;
        #pragma unroll
        for (int i = 0; i < NTW; i++) {
            int col = (wv + 4 * i) * 16 + lh;
            if (col < 300) s += __expf(acc[i][j] - M[j]);
        }
        s += __shfl_xor(s, 1, 16);
        s += __shfl_xor(s, 2, 16);
        s += __shfl_xor(s, 4, 16);
        s += __shfl_xor(s, 8, 16);
        S[j] = s;
    }
    if (lh == 0) {
        #pragma unroll
        for (int j = 0; j < 4; j++) redS[wv][lq * 4 + j] = S[j];
    }
    __syncthreads();
    float* out1F = (float*)outbase + (size_t)nrows * 128;
    unsigned short* out1B = (unsigned short*)outbase + (size_t)nrows * 128;
    #pragma unroll
    for (int j = 0; j < 4; j++) {
        int rl = lq * 4 + j;
        float Sall = (redS[0][rl] + redS[1][rl]) + (redS[2][rl] + redS[3][rl]);
        float L = M[j] + __logf(Sall);
        int rg = row0 + rl;
        if (rg < nrows) {
            #pragma unroll
            for (int i = 0; i < NTW; i++) {
                int col = (wv + 4 * i) * 16 + lh;
                if (col < 300) {
                    float v = acc[i][j] - L;
                    if (xf32) out1F[(size_t)rg * 300 + col] = v;
                    else      out1B[(size_t)rg * 300 + col] = f2bf(v);
                }
            }
        }
    }
}

// ---------------------------------------------------------------------------
extern "C" void kernel_launch(void* const* d_in, const int* in_sizes, int n_in,
                              void* d_out, int out_size, void* d_ws, size_t ws_size,
                              hipStream_t stream)
{
    const void* x     = d_in[0];
    const int*  ei    = (const int*)d_in[1];
    const void* Wl    = d_in[2];
    const void* bl    = d_in[3];
    const void* Wr    = d_in[4];
    const void* Wsk   = d_in[5];
    const void* bsk   = d_in[6];
    const void* gamma = d_in[7];
    const void* beta  = d_in[8];
    const void* rmean = d_in[9];
    const void* rvar  = d_in[10];
    const void* Wlo   = d_in[11];
    const void* blo   = d_in[12];
    const void* Wro   = d_in[13];

    int N = in_sizes[0] / 128;
    int E = in_sizes[1] / 2;
    long nelem = (long)N * 128;
    bool idx16 = (N <= 65535);

    char* ws = (char*)d_ws;
    size_t off = 0;
    unsigned short* xbf   = (unsigned short*)(ws + off); off += (size_t)N * 128 * 2;
    unsigned short* meanB = (unsigned short*)(ws + off); off += (size_t)N * 128 * 2;
    unsigned int* x8      = (unsigned int*)(ws + off);   off += (size_t)N * 128;
    unsigned int* xemb8   = (unsigned int*)(ws + off);   off += (size_t)N * 128;
    off = (off + 255) & ~(size_t)255;
    int* deg    = (int*)(ws + off);           off += (size_t)N * 4;
    int* scnt   = (int*)(ws + off);           off += 256;   // zeroed with deg
    int* rowptr = (int*)(ws + off);           off += (size_t)N * 4;
    int* rank   = (int*)(ws + off);           off += (size_t)E * 4;
    unsigned int* ds32 = (unsigned int*)(ws + off); off += (size_t)E * 4;
    int* aux    = (int*)(ws + off);           off += 256;
    void* adjv  = (void*)(ws + off);          off += (size_t)E * 4;
    off = (off + 255) & ~(size_t)255;
    unsigned short* W1p = (unsigned short*)(ws + off);  off += 32768 * 2;
    unsigned short* W2p = (unsigned short*)(ws + off);  off += 81920 * 2;
    float* bias1 = (float*)(ws + off);        off += 512;
    float* bias2 = (float*)(ws + off);        off += 1280;

    int egrid  = (E + 255) / 256;
    int sblk   = (N + 1023) / 1024;
    int agrid  = (N + 3) / 4;
    int g1grid = (N + 31) / 32;
    int g2grid = (N + 15) / 16;
    int tgrid  = (int)((nelem / 8 + 255) / 256);

    const unsigned int* xprobe = (const unsigned int*)x;

    // deg + scnt must be zero before k_front / k_scan.
    hipMemsetAsync(deg, 0, (size_t)N * 4 + 256, stream);

    // rank || tobf interleaved by parity, fold at the tail.
    k_front<<<egrid + tgrid + 449, 256, 0, stream>>>(
        ei, deg, rank, ds32, E, N, idx16 ? 1 : 0, egrid,
        x, xbf, x8, nelem, tgrid,
        Wl, Wr, Wsk, gamma, rvar, bl, bsk, rmean, beta, Wlo, blo, Wro,
        W1p, W2p, bias1, bias2);

    // fused two-level scan (last block does the aux fixup).
    k_scan<<<sblk, 256, 0, stream>>>(deg, rowptr, aux, scnt, N, sblk);

    if (idx16) {
        unsigned short* adj = (unsigned short*)adjv;
        k_place16<<<egrid, 256, 0, stream>>>(ds32, rowptr, aux, rank, adj, E, N);
        k_agg<unsigned short><<<agrid, 256, 0, stream>>>(x8, rowptr, aux, deg, adj, meanB, N);
        k_gemm1<<<g1grid, 256, 0, stream>>>(meanB, xbf, xprobe, W1p, bias1, d_out, xemb8, N);
        k_agg<unsigned short><<<agrid, 256, 0, stream>>>(xemb8, rowptr, aux, deg, adj, meanB, N);
        k_gemm2<<<g2grid, 256, 0, stream>>>(meanB, xemb8, xprobe, W2p, bias2, d_out, N);
    } else {
        int* adj = (int*)adjv;
        k_place32<<<egrid, 256, 0, stream>>>(ei, rowptr, aux, rank, adj, E, N);
        k_agg<int><<<agrid, 256, 0, stream>>>(x8, rowptr, aux, deg, adj, meanB, N);
        k_gemm1<<<g1grid, 256, 0, stream>>>(meanB, xbf, xprobe, W1p, bias1, d_out, xemb8, N);
        k_agg<int><<<agrid, 256, 0, stream>>>(xemb8, rowptr, aux, deg, adj, meanB, N);
        k_gemm2<<<g2grid, 256, 0, stream>>>(meanB, xemb8, xprobe, W2p, bias2, d_out, N);
    }
}